// Round 3
// baseline (218.205 us; speedup 1.0000x reference)
//
#include <hip/hip_runtime.h>
#include <cstdint>

// Problem constants (from reference)
#define B 64
#define P 5000
#define G 300
#define C 20
#define SCALE_F 512.0f
#define IOU_TH 0.5f
#define NT 1024
#define NSPLIT 4                              // blocks per image
#define PCHUNK ((P + NSPLIT - 1) / NSPLIT)    // 1250 preds per block
#define PPT ((PCHUNK + NT - 1) / NT)          // 2

// Match numpy float32 semantics exactly: no FMA contraction (hipcc defaults
// to contract=fast). Division stays IEEE (no fast-math).
#pragma clang fp contract(off)

// ---------------------------------------------------------------------------
// One launch, grid = (NSPLIT, B) x 1024 threads = 256 blocks (full chip).
// Each block: stable class-sort of its image's targets in LDS (cheap, redone
// per block), match its 1250-pred chunk against the class bucket, claim
// targets via device-scope atomicMin on global firstp (sentinel 0xFFFFFFFF
// from memset). Decoupled completion: release fence + per-image arrival
// counter; the last-arriving block acquire-fences and resolves the whole
// image (first eligible claimant of each target wins). No spinning -> no
// co-residency assumption.
// Key identity: the reference argmax does not depend on `detected`, so the
// sequential scan == "first eligible claimant per target".
// ---------------------------------------------------------------------------
__global__ __launch_bounds__(NT) void fused_kernel(
    const float* __restrict__ preds,      // [B,P,6]
    const float* __restrict__ labels,     // [B,G,5]
    float* __restrict__ out_stats,        // [B,P,3]
    float* __restrict__ out_tcls,         // [B,G]
    unsigned int* __restrict__ gfirstp,   // [B,G]  pre-memset 0xFF
    int* __restrict__ gbest,              // [B,P]
    unsigned int* __restrict__ counters)  // [B]    pre-memset 0
{
    const int s = blockIdx.x;
    const int b = blockIdx.y;
    const int tid = threadIdx.x;

    __shared__ float4 sb[G];      // class-sorted scaled boxes
    __shared__ float  sa[G];      // areas
    __shared__ int    ssi[G];     // sorted pos -> original target idx
    __shared__ int    so[C + 1];  // bucket offsets
    __shared__ int    cls_s[G];
    __shared__ int    cnt[C];
    __shared__ unsigned int lf[G];     // firstp staged for resolve
    __shared__ unsigned int arrival;

    const float* lab = labels + (size_t)b * G * 5;

    if (tid < C) cnt[tid] = 0;
    for (int t = tid; t < G; t += NT) {
        float c = lab[t * 5 + 4];
        cls_s[t] = (int)c;
        if (s == 0) out_tcls[b * G + t] = c;
    }
    __syncthreads();

    for (int t = tid; t < G; t += NT) atomicAdd(&cnt[cls_s[t]], 1);
    __syncthreads();

    if (tid == 0) {
        int acc = 0;
        for (int c = 0; c < C; ++c) { so[c] = acc; acc += cnt[c]; }
        so[C] = acc;
    }
    __syncthreads();

    // stable rank + scatter (preserves original order within a class ->
    // jnp.argmax first-occurrence tie-break preserved)
    for (int t = tid; t < G; t += NT) {
        int c = cls_s[t];
        int rank = 0;
        for (int u = 0; u < t; ++u) rank += (cls_s[u] == c) ? 1 : 0;
        int pos = so[c] + rank;
        float x1 = lab[t * 5 + 0] * SCALE_F;   // *512 exact (pow2)
        float y1 = lab[t * 5 + 1] * SCALE_F;
        float x2 = lab[t * 5 + 2] * SCALE_F;
        float y2 = lab[t * 5 + 3] * SCALE_F;
        sb[pos] = make_float4(x1, y1, x2, y2);
        sa[pos] = (x2 - x1) * (y2 - y1);
        ssi[pos] = t;
    }
    __syncthreads();

    // ---- match phase: this block's pred chunk ----
    const int pbase = s * PCHUNK;
    #pragma unroll
    for (int k = 0; k < PPT; ++k) {
        int p = pbase + k * NT + tid;
        if (p >= pbase + PCHUNK || p >= P) continue;
        const float* pr = preds + ((size_t)b * P + p) * 6;
        float px1 = pr[0] * SCALE_F;
        float py1 = pr[1] * SCALE_F;
        float px2 = pr[2] * SCALE_F;
        float py2 = pr[3] * SCALE_F;
        float score = pr[4];
        float fcls = pr[5];
        int c = (int)fcls;
        float parea = (px2 - px1) * (py2 - py1);

        int lo = so[c], hi = so[c + 1];
        float best = -1.0f;
        int bi = -1;
        for (int j = lo; j < hi; ++j) {
            float4 tb = sb[j];
            float lx = fmaxf(px1, tb.x);
            float ly = fmaxf(py1, tb.y);
            float rx = fminf(px2, tb.z);
            float ry = fminf(py2, tb.w);
            float w = fmaxf(rx - lx, 0.0f);
            float h = fmaxf(ry - ly, 0.0f);
            float inter = w * h;
            float uni = (parea + sa[j]) - inter;   // reference assoc order
            float iou = inter / uni;               // IEEE div
            if (iou > best) { best = iou; bi = ssi[j]; }  // strict >: first max
        }

        bool eligible = (score > 0.0f) && (hi > lo) && (best > IOU_TH);
        size_t op = (size_t)b * P + p;
        gbest[op] = eligible ? bi : -1;
        if (eligible) atomicMin(&gfirstp[b * G + bi], (unsigned int)p);
        out_stats[op * 3 + 1] = score;
        out_stats[op * 3 + 2] = fcls;
    }

    // ---- release: my stores visible device-wide, then signal arrival ----
    __threadfence();
    __syncthreads();
    if (tid == 0) arrival = atomicAdd(&counters[b], 1u);
    __syncthreads();
    if (arrival != NSPLIT - 1) return;   // not last block for this image

    // ---- last block: acquire, then resolve the whole image ----
    __threadfence();
    for (int t = tid; t < G; t += NT) lf[t] = gfirstp[b * G + t];
    __syncthreads();

    for (int p = tid; p < P; p += NT) {
        size_t op = (size_t)b * P + p;
        int bi = gbest[op];
        float corr = (bi >= 0 && lf[bi] == (unsigned int)p) ? 1.0f : 0.0f;
        out_stats[op * 3 + 0] = corr;
    }
}

extern "C" void kernel_launch(void* const* d_in, const int* in_sizes, int n_in,
                              void* d_out, int out_size, void* d_ws, size_t ws_size,
                              hipStream_t stream) {
    const float* output = (const float*)d_in[0];   // [B,P,6]
    const float* labels = (const float*)d_in[1];   // [B,G,5]

    float* out_stats = (float*)d_out;                       // [B,P,3]
    float* out_tcls  = (float*)d_out + (size_t)B * P * 3;   // [B,G]

    // workspace layout
    unsigned int* gfirstp  = (unsigned int*)d_ws;           // B*G
    unsigned int* counters = gfirstp + B * G;               // B
    int* gbest             = (int*)(counters + B);          // B*P

    hipMemsetAsync(gfirstp, 0xFF, (size_t)B * G * 4, stream);
    hipMemsetAsync(counters, 0, (size_t)B * 4, stream);

    dim3 grid(NSPLIT, B);
    fused_kernel<<<grid, NT, 0, stream>>>(output, labels, out_stats, out_tcls,
                                          gfirstp, gbest, counters);
}

// Round 4
// 84.130 us; speedup vs baseline: 2.5937x; 2.5937x over previous
//
#include <hip/hip_runtime.h>
#include <cstdint>

// Problem constants (from reference)
#define B 64
#define P 5000
#define G 300
#define C 20
#define SCALE_F 512.0f
#define IOU_TH 0.5f
#define NT 1024
#define PPT ((P + NT - 1) / NT)   // 5 slots per thread

// Match numpy float32 semantics exactly: no FMA contraction (hipcc defaults
// to contract=fast). Division stays IEEE (no fast-math).
#pragma clang fp contract(off)

// ---------------------------------------------------------------------------
// One block per image, everything in LDS, NO cross-block communication
// (round-3 lesson: device-scope fences on gfx950 = per-wave L2 flush = 10x
// regression; producer->consumer must stay inside a block or cross a kernel
// boundary).
//
// Phases (all in-block):
//  1. stable counting sort of targets by class (stability preserves the
//     jnp.argmax first-occurrence tie-break)
//  2. UNSTABLE counting sort of prediction indices by class (predictions are
//     independent; sorting makes wave lanes process same-class preds ->
//     uniform bucket bounds + broadcast LDS reads of target boxes)
//  3. match: per-pred argmax-IoU over its class bucket; eligible preds claim
//     their target via LDS atomicMin(firstp[bi], p)
//  4. resolve: correct[p] = eligible(p) && firstp[bi(p)] == p
// Key identity: the reference argmax does not depend on `detected`, so the
// sequential scan == "first eligible claimant (lowest p) per target wins".
// ---------------------------------------------------------------------------
__global__ __launch_bounds__(NT) void fused_kernel(
    const float* __restrict__ preds,    // [B,P,6]
    const float* __restrict__ labels,   // [B,G,5]
    float* __restrict__ out_stats,      // [B,P,3]
    float* __restrict__ out_tcls)       // [B,G]
{
    const int b = blockIdx.x;
    const int tid = threadIdx.x;

    __shared__ float4 sb[G];            // class-sorted scaled target boxes
    __shared__ float  sa[G];            // class-sorted target areas
    __shared__ short  ssi[G];           // sorted pos -> original target idx
    __shared__ short  cls_s[G];         // target class (original order)
    __shared__ int    so[C + 1];        // target bucket offsets
    __shared__ int    cnt[C];           // target histogram
    __shared__ int    firstp[G];        // lowest eligible p claiming target
    __shared__ int    poff[C + 1];      // pred bucket offsets
    __shared__ int    pcnt[C];          // pred histogram, then running offset
    __shared__ unsigned short psorted[P]; // sorted slot -> pred idx
    __shared__ short  pbi[P];           // pred idx -> best target idx or -1

    const float* lab = labels + (size_t)b * G * 5;
    const float* prd = preds + (size_t)b * P * 6;

    // ---- phase 0: init + load target classes ----
    if (tid < C) { cnt[tid] = 0; pcnt[tid] = 0; }
    for (int t = tid; t < G; t += NT) {
        float c = lab[t * 5 + 4];
        cls_s[t] = (short)(int)c;
        out_tcls[b * G + t] = c;
        firstp[t] = 0x7FFFFFFF;
    }
    __syncthreads();

    // ---- phase 1: histograms; emit score/cls coalesced ----
    for (int t = tid; t < G; t += NT) atomicAdd(&cnt[cls_s[t]], 1);
    #pragma unroll
    for (int k = 0; k < PPT; ++k) {
        int p = tid + k * NT;
        if (p < P) {
            float score = prd[p * 6 + 4];
            float fcls  = prd[p * 6 + 5];
            atomicAdd(&pcnt[(int)fcls], 1);
            size_t op = (size_t)b * P + p;
            out_stats[op * 3 + 1] = score;
            out_stats[op * 3 + 2] = fcls;
        }
    }
    __syncthreads();

    // ---- phase 2: exclusive scans (two serial threads, different waves) ----
    if (tid == 0) {
        int a = 0;
        for (int c = 0; c < C; ++c) { so[c] = a; a += cnt[c]; }
        so[C] = a;
    }
    if (tid == 64) {
        int a = 0;
        for (int c = 0; c < C; ++c) { int v = pcnt[c]; poff[c] = a; pcnt[c] = a; a += v; }
        poff[C] = a;
    }
    __syncthreads();

    // ---- phase 3a: STABLE target scatter (rank = same-class preds before t) ----
    for (int t = tid; t < G; t += NT) {
        short c = cls_s[t];
        int rank = 0;
        for (int u = 0; u < t; ++u) rank += (cls_s[u] == c) ? 1 : 0;
        int pos = so[c] + rank;
        float x1 = lab[t * 5 + 0] * SCALE_F;   // *512 exact (pow2)
        float y1 = lab[t * 5 + 1] * SCALE_F;
        float x2 = lab[t * 5 + 2] * SCALE_F;
        float y2 = lab[t * 5 + 3] * SCALE_F;
        sb[pos] = make_float4(x1, y1, x2, y2);
        sa[pos] = (x2 - x1) * (y2 - y1);
        ssi[pos] = (short)t;
    }
    // ---- phase 3b: unstable pred scatter ----
    #pragma unroll
    for (int k = 0; k < PPT; ++k) {
        int p = tid + k * NT;
        if (p < P) {
            int c = (int)prd[p * 6 + 5];          // L2-hot re-read
            int pos = atomicAdd(&pcnt[c], 1);
            psorted[pos] = (unsigned short)p;
        }
    }
    __syncthreads();

    // ---- phase 4: match (slot-ordered: lanes mostly same class) ----
    #pragma unroll
    for (int k = 0; k < PPT; ++k) {
        int slot = tid + k * NT;
        if (slot >= P) continue;
        int p = psorted[slot];
        const float* pr = prd + p * 6;
        float px1 = pr[0] * SCALE_F;
        float py1 = pr[1] * SCALE_F;
        float px2 = pr[2] * SCALE_F;
        float py2 = pr[3] * SCALE_F;
        float score = pr[4];
        int c = (int)pr[5];
        float parea = (px2 - px1) * (py2 - py1);

        int lo = so[c], hi = so[c + 1];
        float best = -1.0f;
        int bi = -1;
        // bucket preserves original order; strict > keeps FIRST max occurrence
        for (int j = lo; j < hi; ++j) {
            float4 tb = sb[j];                 // wave-uniform j -> broadcast
            float lx = fmaxf(px1, tb.x);
            float ly = fmaxf(py1, tb.y);
            float rx = fminf(px2, tb.z);
            float ry = fminf(py2, tb.w);
            float w = fmaxf(rx - lx, 0.0f);
            float h = fmaxf(ry - ly, 0.0f);
            float inter = w * h;
            float uni = (parea + sa[j]) - inter;   // reference assoc order
            float iou = inter / uni;               // IEEE div
            if (iou > best) { best = iou; bi = ssi[j]; }
        }

        bool eligible = (score > 0.0f) && (hi > lo) && (best > IOU_TH);
        pbi[p] = eligible ? (short)bi : (short)-1;
        if (eligible) atomicMin(&firstp[bi], p);
    }
    __syncthreads();

    // ---- phase 5: resolve (coalesced over p) ----
    #pragma unroll
    for (int k = 0; k < PPT; ++k) {
        int p = tid + k * NT;
        if (p >= P) continue;
        int bi = pbi[p];
        float corr = (bi >= 0 && firstp[bi] == p) ? 1.0f : 0.0f;
        out_stats[((size_t)b * P + p) * 3 + 0] = corr;
    }
}

extern "C" void kernel_launch(void* const* d_in, const int* in_sizes, int n_in,
                              void* d_out, int out_size, void* d_ws, size_t ws_size,
                              hipStream_t stream) {
    const float* output = (const float*)d_in[0];   // [B,P,6]
    const float* labels = (const float*)d_in[1];   // [B,G,5]

    float* out_stats = (float*)d_out;                       // [B,P,3]
    float* out_tcls  = (float*)d_out + (size_t)B * P * 3;   // [B,G]

    fused_kernel<<<B, NT, 0, stream>>>(output, labels, out_stats, out_tcls);
}

// Round 5
// 77.297 us; speedup vs baseline: 2.8229x; 1.0884x over previous
//
#include <hip/hip_runtime.h>
#include <cstdint>

// Problem constants (from reference)
#define B 64
#define P 5000
#define G 300
#define C 20
#define SCALE_F 512.0f
#define IOU_TH 0.5f
#define NSPLIT 4                              // pred chunks per image
#define PCHUNK ((P + NSPLIT - 1) / NSPLIT)    // 1250
#define NTA 512
#define SPT ((PCHUNK + NTA - 1) / NTA)        // 3 slots per thread

// Match numpy float32 semantics exactly: no FMA contraction (hipcc defaults
// to contract=fast). Division stays IEEE (no fast-math).
#pragma clang fp contract(off)

// ---------------------------------------------------------------------------
// Kernel A: grid (NSPLIT, B) = 256 blocks (full chip), 512 threads.
// Per block: stable class-sort of its image's targets in LDS (stability
// preserves the jnp.argmax first-occurrence tie-break; redone per block,
// ~1us), unstable class-sort of its 1250-pred chunk (wave lanes then process
// same-class preds -> uniform bucket bounds + broadcast LDS reads), match,
// claim via DEVICE-SCOPE atomicMin on global gfirstp. No fences anywhere —
// round-3 lesson: per-wave __threadfence on gfx950 = L2 writeback/invalidate
// storm (10x regression). Cross-kernel visibility comes from the kernel
// boundary (single packet-level flush) + coherent atomics.
// Key identity: the reference argmax does not depend on `detected`, so the
// sequential scan == "first eligible claimant (lowest p) per target wins".
// ---------------------------------------------------------------------------
__global__ __launch_bounds__(NTA) void match_kernel(
    const float* __restrict__ preds,      // [B,P,6]
    const float* __restrict__ labels,     // [B,G,5]
    float* __restrict__ out_stats,        // [B,P,3]
    float* __restrict__ out_tcls,         // [B,G]
    unsigned int* __restrict__ gfirstp,   // [B,G]  pre-memset 0xFF
    short* __restrict__ gbest)            // [B,P]
{
    const int s = blockIdx.x;
    const int b = blockIdx.y;
    const int tid = threadIdx.x;

    __shared__ float4 sb[G];              // class-sorted scaled target boxes
    __shared__ float  sa[G];              // areas
    __shared__ short  ssi[G];             // sorted pos -> original target idx
    __shared__ short  cls_s[G];           // target class (original order)
    __shared__ int    so[C + 1];          // target bucket offsets
    __shared__ int    cnt[C];
    __shared__ int    pcnt[C];            // pred histogram -> running offset
    __shared__ unsigned short psorted[PCHUNK]; // slot -> global pred idx

    const float* lab = labels + (size_t)b * G * 5;
    const float* prd = preds + (size_t)b * P * 6;
    const int pbase = s * PCHUNK;

    // ---- init + target classes ----
    if (tid < C) { cnt[tid] = 0; pcnt[tid] = 0; }
    for (int t = tid; t < G; t += NTA) {
        float c = lab[t * 5 + 4];
        cls_s[t] = (short)(int)c;
        if (s == 0) out_tcls[b * G + t] = c;
    }
    __syncthreads();

    // ---- histograms; emit score/cls for this chunk ----
    for (int t = tid; t < G; t += NTA) atomicAdd(&cnt[cls_s[t]], 1);
    #pragma unroll
    for (int k = 0; k < SPT; ++k) {
        int p = pbase + k * NTA + tid;
        if (p < pbase + PCHUNK && p < P) {
            float score = prd[p * 6 + 4];
            float fcls  = prd[p * 6 + 5];
            atomicAdd(&pcnt[(int)fcls], 1);
            size_t op = (size_t)b * P + p;
            out_stats[op * 3 + 1] = score;
            out_stats[op * 3 + 2] = fcls;
        }
    }
    __syncthreads();

    // ---- exclusive scans (two serial threads in different waves) ----
    if (tid == 0) {
        int a = 0;
        for (int c = 0; c < C; ++c) { so[c] = a; a += cnt[c]; }
        so[C] = a;
    }
    if (tid == 64) {
        int a = 0;
        for (int c = 0; c < C; ++c) { int v = pcnt[c]; pcnt[c] = a; a += v; }
    }
    __syncthreads();

    // ---- stable target scatter ----
    for (int t = tid; t < G; t += NTA) {
        short c = cls_s[t];
        int rank = 0;
        for (int u = 0; u < t; ++u) rank += (cls_s[u] == c) ? 1 : 0;
        int pos = so[c] + rank;
        float x1 = lab[t * 5 + 0] * SCALE_F;   // *512 exact (pow2)
        float y1 = lab[t * 5 + 1] * SCALE_F;
        float x2 = lab[t * 5 + 2] * SCALE_F;
        float y2 = lab[t * 5 + 3] * SCALE_F;
        sb[pos] = make_float4(x1, y1, x2, y2);
        sa[pos] = (x2 - x1) * (y2 - y1);
        ssi[pos] = (short)t;
    }
    // ---- unstable pred scatter (order within bucket irrelevant) ----
    #pragma unroll
    for (int k = 0; k < SPT; ++k) {
        int p = pbase + k * NTA + tid;
        if (p < pbase + PCHUNK && p < P) {
            int c = (int)prd[p * 6 + 5];      // L2-hot re-read
            int pos = atomicAdd(&pcnt[c], 1);
            psorted[pos] = (unsigned short)p;
        }
    }
    __syncthreads();

    // ---- match (slot-ordered: lanes mostly same class) ----
    #pragma unroll
    for (int k = 0; k < SPT; ++k) {
        int slot = k * NTA + tid;
        if (slot >= PCHUNK) continue;
        int p = psorted[slot];
        const float* pr = prd + p * 6;
        float px1 = pr[0] * SCALE_F;
        float py1 = pr[1] * SCALE_F;
        float px2 = pr[2] * SCALE_F;
        float py2 = pr[3] * SCALE_F;
        float score = pr[4];
        int c = (int)pr[5];
        float parea = (px2 - px1) * (py2 - py1);

        int lo = so[c], hi = so[c + 1];
        float best = -1.0f;
        int bi = -1;
        // bucket preserves original order; strict > keeps FIRST max occurrence
        for (int j = lo; j < hi; ++j) {
            float4 tb = sb[j];                 // wave-uniform j -> broadcast
            float lx = fmaxf(px1, tb.x);
            float ly = fmaxf(py1, tb.y);
            float rx = fminf(px2, tb.z);
            float ry = fminf(py2, tb.w);
            float w = fmaxf(rx - lx, 0.0f);
            float h = fmaxf(ry - ly, 0.0f);
            float inter = w * h;
            float uni = (parea + sa[j]) - inter;   // reference assoc order
            float iou = inter / uni;               // IEEE div
            if (iou > best) { best = iou; bi = ssi[j]; }
        }

        bool eligible = (score > 0.0f) && (hi > lo) && (best > IOU_TH);
        gbest[(size_t)b * P + p] = eligible ? (short)bi : (short)-1;
        if (eligible) atomicMin(&gfirstp[b * G + bi], (unsigned int)p);
    }
}

// ---------------------------------------------------------------------------
// Kernel B: resolve. First (lowest p) eligible claimant of each target wins.
// Kernel boundary guarantees visibility of kernel A's stores/atomics.
// ---------------------------------------------------------------------------
__global__ __launch_bounds__(256) void resolve_kernel(
    const unsigned int* __restrict__ gfirstp,
    const short* __restrict__ gbest,
    float* __restrict__ out_stats)
{
    int i = blockIdx.x * 256 + threadIdx.x;   // over B*P
    if (i >= B * P) return;
    int b = i / P;
    int p = i - b * P;
    int bi = gbest[i];
    float corr = (bi >= 0 && gfirstp[b * G + bi] == (unsigned int)p) ? 1.0f : 0.0f;
    out_stats[(size_t)i * 3 + 0] = corr;
}

extern "C" void kernel_launch(void* const* d_in, const int* in_sizes, int n_in,
                              void* d_out, int out_size, void* d_ws, size_t ws_size,
                              hipStream_t stream) {
    const float* output = (const float*)d_in[0];   // [B,P,6]
    const float* labels = (const float*)d_in[1];   // [B,G,5]

    float* out_stats = (float*)d_out;                       // [B,P,3]
    float* out_tcls  = (float*)d_out + (size_t)B * P * 3;   // [B,G]

    // workspace layout
    unsigned int* gfirstp = (unsigned int*)d_ws;            // B*G
    short* gbest          = (short*)(gfirstp + B * G);      // B*P

    hipMemsetAsync(gfirstp, 0xFF, (size_t)B * G * 4, stream);

    dim3 grid(NSPLIT, B);
    match_kernel<<<grid, NTA, 0, stream>>>(output, labels, out_stats, out_tcls,
                                           gfirstp, gbest);
    resolve_kernel<<<(B * P + 255) / 256, 256, 0, stream>>>(gfirstp, gbest, out_stats);
}

// Round 6
// 76.186 us; speedup vs baseline: 2.8641x; 1.0146x over previous
//
#include <hip/hip_runtime.h>
#include <cstdint>

// Problem constants (from reference)
#define B 64
#define P 5000
#define G 300
#define C 20
#define SCALE_F 512.0f
#define IOU_TH 0.5f
#define NSPLIT 4                              // pred chunks per image
#define PCHUNK ((P + NSPLIT - 1) / NSPLIT)    // 1250
#define NTA 512
#define SPT ((PCHUNK + NTA - 1) / NTA)        // 3 slots per thread
#define SENT 0x7FFFFFFF

// Match numpy float32 semantics exactly: no FMA contraction (hipcc defaults
// to contract=fast). Division stays IEEE (no fast-math).
#pragma clang fp contract(off)

// ---------------------------------------------------------------------------
// Kernel A: grid (NSPLIT, B) = 256 blocks (full chip), 512 threads.
// Per block: stable class-sort of its image's targets in LDS (stability
// preserves the jnp.argmax first-occurrence tie-break), unstable class-sort
// of its 1250-pred chunk (wave lanes then process same-class preds ->
// uniform bucket bounds + broadcast LDS reads), match, claim via LDS
// atomicMin into a block-private firstp, then dump it to blockfp[b][s][*].
// NO global atomics, NO fences, NO global init needed (each block writes its
// own sentinel) — round-3 lesson: per-wave __threadfence on gfx950 = L2
// flush storm; cross-kernel visibility comes from the kernel boundary.
// Key identity: the reference argmax does not depend on `detected`, so the
// sequential scan == "first eligible claimant (lowest p) per target wins".
// ---------------------------------------------------------------------------
__global__ __launch_bounds__(NTA) void match_kernel(
    const float* __restrict__ preds,      // [B,P,6]
    const float* __restrict__ labels,     // [B,G,5]
    int* __restrict__ blockfp,            // [B,NSPLIT,G]
    short* __restrict__ gbest)            // [B,P]
{
    const int s = blockIdx.x;
    const int b = blockIdx.y;
    const int tid = threadIdx.x;

    __shared__ float4 sb[G];              // class-sorted scaled target boxes
    __shared__ float  sa[G];              // areas
    __shared__ short  ssi[G];             // sorted pos -> original target idx
    __shared__ short  cls_s[G];           // target class (original order)
    __shared__ int    so[C + 1];          // target bucket offsets
    __shared__ int    cnt[C];
    __shared__ int    pcnt[C];            // pred histogram -> running offset
    __shared__ int    firstp[G];          // chunk-local lowest claimant
    __shared__ unsigned short psorted[PCHUNK]; // slot -> global pred idx

    const float* lab = labels + (size_t)b * G * 5;
    const float* prd = preds + (size_t)b * P * 6;
    const int pbase = s * PCHUNK;

    // ---- init + target classes ----
    if (tid < C) { cnt[tid] = 0; pcnt[tid] = 0; }
    for (int t = tid; t < G; t += NTA) {
        cls_s[t] = (short)(int)lab[t * 5 + 4];
        firstp[t] = SENT;
    }
    __syncthreads();

    // ---- histograms ----
    for (int t = tid; t < G; t += NTA) atomicAdd(&cnt[cls_s[t]], 1);
    #pragma unroll
    for (int k = 0; k < SPT; ++k) {
        int p = pbase + k * NTA + tid;
        if (p < pbase + PCHUNK)
            atomicAdd(&pcnt[(int)prd[p * 6 + 5]], 1);
    }
    __syncthreads();

    // ---- exclusive scans (two serial threads in different waves) ----
    if (tid == 0) {
        int a = 0;
        for (int c = 0; c < C; ++c) { so[c] = a; a += cnt[c]; }
        so[C] = a;
    }
    if (tid == 64) {
        int a = 0;
        for (int c = 0; c < C; ++c) { int v = pcnt[c]; pcnt[c] = a; a += v; }
    }
    __syncthreads();

    // ---- stable target scatter ----
    for (int t = tid; t < G; t += NTA) {
        short c = cls_s[t];
        int rank = 0;
        for (int u = 0; u < t; ++u) rank += (cls_s[u] == c) ? 1 : 0;
        int pos = so[c] + rank;
        float x1 = lab[t * 5 + 0] * SCALE_F;   // *512 exact (pow2)
        float y1 = lab[t * 5 + 1] * SCALE_F;
        float x2 = lab[t * 5 + 2] * SCALE_F;
        float y2 = lab[t * 5 + 3] * SCALE_F;
        sb[pos] = make_float4(x1, y1, x2, y2);
        sa[pos] = (x2 - x1) * (y2 - y1);
        ssi[pos] = (short)t;
    }
    // ---- unstable pred scatter (order within bucket irrelevant) ----
    #pragma unroll
    for (int k = 0; k < SPT; ++k) {
        int p = pbase + k * NTA + tid;
        if (p < pbase + PCHUNK) {
            int c = (int)prd[p * 6 + 5];      // L2-hot re-read
            int pos = atomicAdd(&pcnt[c], 1);
            psorted[pos] = (unsigned short)p;
        }
    }
    __syncthreads();

    // ---- match (slot-ordered: lanes mostly same class) ----
    #pragma unroll
    for (int k = 0; k < SPT; ++k) {
        int slot = k * NTA + tid;
        if (slot >= PCHUNK) continue;
        int p = psorted[slot];
        const float* pr = prd + p * 6;
        float px1 = pr[0] * SCALE_F;
        float py1 = pr[1] * SCALE_F;
        float px2 = pr[2] * SCALE_F;
        float py2 = pr[3] * SCALE_F;
        float score = pr[4];
        int c = (int)pr[5];
        float parea = (px2 - px1) * (py2 - py1);

        int lo = so[c], hi = so[c + 1];
        float best = -1.0f;
        int bi = -1;
        // bucket preserves original order; strict > keeps FIRST max occurrence
        for (int j = lo; j < hi; ++j) {
            float4 tb = sb[j];                 // wave-uniform j -> broadcast
            float lx = fmaxf(px1, tb.x);
            float ly = fmaxf(py1, tb.y);
            float rx = fminf(px2, tb.z);
            float ry = fminf(py2, tb.w);
            float w = fmaxf(rx - lx, 0.0f);
            float h = fmaxf(ry - ly, 0.0f);
            float inter = w * h;
            float uni = (parea + sa[j]) - inter;   // reference assoc order
            float iou = inter / uni;               // IEEE div
            if (iou > best) { best = iou; bi = ssi[j]; }
        }

        bool eligible = (score > 0.0f) && (hi > lo) && (best > IOU_TH);
        gbest[(size_t)b * P + p] = eligible ? (short)bi : (short)-1;
        if (eligible) atomicMin(&firstp[bi], p);
    }
    __syncthreads();

    // ---- dump chunk-local claims (coalesced) ----
    for (int t = tid; t < G; t += NTA)
        blockfp[((size_t)b * NSPLIT + s) * G + t] = firstp[t];
}

// ---------------------------------------------------------------------------
// Kernel B: resolve. min over the 4 chunk-local claim arrays = global first
// claimant; sole writer of out_stats (12 contiguous bytes per pred) and
// out_tcls. Kernel boundary guarantees visibility of kernel A's stores.
// ---------------------------------------------------------------------------
__global__ __launch_bounds__(1024) void resolve_kernel(
    const float* __restrict__ preds,      // [B,P,6]
    const float* __restrict__ labels,     // [B,G,5]
    const int* __restrict__ blockfp,      // [B,NSPLIT,G]
    const short* __restrict__ gbest,      // [B,P]
    float* __restrict__ out_stats,        // [B,P,3]
    float* __restrict__ out_tcls)         // [B,G]
{
    const int s = blockIdx.x;
    const int b = blockIdx.y;
    const int tid = threadIdx.x;

    __shared__ int lf[G];

    if (tid < G) {
        const int* fp = blockfp + (size_t)b * NSPLIT * G + tid;
        int m = fp[0];
        m = min(m, fp[G]);
        m = min(m, fp[2 * G]);
        m = min(m, fp[3 * G]);
        lf[tid] = m;
        if (s == 0) out_tcls[b * G + tid] = labels[((size_t)b * G + tid) * 5 + 4];
    }
    __syncthreads();

    const int pbase = s * PCHUNK;
    #pragma unroll
    for (int k = 0; k < 2; ++k) {
        int p = pbase + k * 1024 + tid;
        if (p >= pbase + PCHUNK) continue;
        size_t ip = (size_t)b * P + p;
        int bi = gbest[ip];
        float corr = (bi >= 0 && lf[bi] == p) ? 1.0f : 0.0f;
        out_stats[ip * 3 + 0] = corr;
        out_stats[ip * 3 + 1] = preds[ip * 6 + 4];
        out_stats[ip * 3 + 2] = preds[ip * 6 + 5];
    }
}

extern "C" void kernel_launch(void* const* d_in, const int* in_sizes, int n_in,
                              void* d_out, int out_size, void* d_ws, size_t ws_size,
                              hipStream_t stream) {
    const float* output = (const float*)d_in[0];   // [B,P,6]
    const float* labels = (const float*)d_in[1];   // [B,G,5]

    float* out_stats = (float*)d_out;                       // [B,P,3]
    float* out_tcls  = (float*)d_out + (size_t)B * P * 3;   // [B,G]

    // workspace layout (no init required — kernel A writes every slot)
    int* blockfp = (int*)d_ws;                              // B*NSPLIT*G
    short* gbest = (short*)(blockfp + (size_t)B * NSPLIT * G); // B*P

    dim3 grid(NSPLIT, B);
    match_kernel<<<grid, NTA, 0, stream>>>(output, labels, blockfp, gbest);
    resolve_kernel<<<grid, 1024, 0, stream>>>(output, labels, blockfp, gbest,
                                              out_stats, out_tcls);
}